// Round 3
// baseline (1553.298 us; speedup 1.0000x reference)
//
#include <hip/hip_runtime.h>

#define T_STEPS 512
#define HS 20       // hidden size
#define F0 10       // input features (layer 0)
#define BPB 6       // batches per block: lane-group g handles batches {g, g+3}
#define NB_TOT 4096
#define NBLK ((NB_TOT + BPB - 1) / BPB)   // 683

__device__ __forceinline__ float sigmoid_fast(float v) {
    return __fdividef(1.f, 1.f + __expf(-v));
}
__device__ __forceinline__ float tanh_fast(float v) {
    return 1.f - __fdividef(2.f, __expf(2.f * v) + 1.f);
}
#define PIN(v) asm volatile("" : "+v"(v))

// 1-gate-per-wave, redundant-finish, ONE barrier per step.
//   waves 0-3: layer0 gates i,f,g,o | waves 4-7: layer1 gates i,f,g,o
//   Each wave: w[40] = 40 floats (+ ~30 misc) ~= 70 regs -> fits 85-reg budget
//   of __launch_bounds__(512,6): 6 waves/SIMD -> 683 blocks (5464 waves, 5.33/SIMD)
//   all co-resident in ONE round (3 blocks/CU x 256 = 768 >= 683).
// Per region t (one __syncthreads at end):
//   L0 wave: finish step t-1 (read packed ex0 float4 written last region by all
//   4 gate waves, update private dup c, dup-write h0(t-1)), then gates(t)
//   reading h0(t-1) = its OWN just-written dup (intra-wave LDS order, no barrier).
//   L1 wave: skewed 2 -> finish step t-3, gates(t-2) reading h0(t-2) (published
//   region t-1, before barrier(t-1)) and h1(t-3) (own dup-write this region).
// All FMA accumulation orders / activation math bit-identical to the verified
// round-2 kernel (bias -> x asc -> h0 asc -> h1 asc; c = sig(f)*c + sig(i)*tanh(g)).
__global__ __launch_bounds__(512, 6)
void lstm2_fc_kernel(const float* __restrict__ x,
                     const float* __restrict__ wih0, const float* __restrict__ whh0,
                     const float* __restrict__ bih0, const float* __restrict__ bhh0,
                     const float* __restrict__ wih1, const float* __restrict__ whh1,
                     const float* __restrict__ bih1, const float* __restrict__ bhh1,
                     const float* __restrict__ wfc,  const float* __restrict__ bfc,
                     float* __restrict__ out)
{
    const int tid   = threadIdx.x;
    const int wid   = tid >> 6;          // 0..7
    const int lane  = tid & 63;
    const int g     = (lane / HS) % 3;   // lanes 60..63 shadow group 0 (benign dups)
    const int u     = lane % HS;
    const int layer = wid >> 2;          // 0: waves 0-3 | 1: waves 4-7
    const int q     = wid & 3;           // gate: 0=i, 1=f, 2=g(tanh), 3=o
    const int bgA   = blockIdx.x * BPB + g;
    const int bgBr  = blockIdx.x * BPB + g + 3;
    const bool okB  = (bgBr < NB_TOT);
    const int bgB   = okB ? bgBr : (NB_TOT - 1);   // clamp reads

    __shared__ float s_h0[2][BPB][HS];      // h0, slot = t&1 for h0(t)
    __shared__ float s_h1[2][BPB][HS];      // h1, slot = s&1 for h1(s)
    __shared__ float ex0[2][BPB][HS][4];    // packed gate activations, layer0
    __shared__ float ex1[2][BPB][HS][4];    // packed gate activations, layer1

    for (int i = tid; i < 2 * BPB * HS; i += 512) {
        (&s_h0[0][0][0])[i] = 0.f;
        (&s_h1[0][0][0])[i] = 0.f;
    }

    // ---- per-lane weights: ONE gate row ----
    // layer0: w[0..9] = wih0 row, w[10..29] = whh0 row (30..39 unused)
    // layer1: w[0..19] = wih1 row, w[20..39] = whh1 row
    float w[2 * HS], bias;
    {
        const int row = q * HS + u;
        if (layer == 0) {
            #pragma unroll
            for (int f = 0; f < F0; ++f) { w[f] = wih0[row * F0 + f]; PIN(w[f]); }
            #pragma unroll
            for (int j = 0; j < HS; ++j) { w[F0 + j] = whh0[row * HS + j]; PIN(w[F0 + j]); }
            bias = bih0[row] + bhh0[row]; PIN(bias);
        } else {
            #pragma unroll
            for (int j = 0; j < HS; ++j) { w[j]      = wih1[row * HS + j]; PIN(w[j]); }
            #pragma unroll
            for (int j = 0; j < HS; ++j) { w[HS + j] = whh1[row * HS + j]; PIN(w[HS + j]); }
            bias = bih1[row] + bhh1[row]; PIN(bias);
        }
    }

    float cA = 0.f, cB = 0.f;   // private dup c per wave (identical across layer's 4 waves)
    const float* xbA = x + (size_t)bgA * (T_STEPS * F0);
    const float* xbB = x + (size_t)bgB * (T_STEPS * F0);

    float2 xnA[F0 / 2], xnB[F0 / 2];   // L0 waves: x(t) prefetched one step ahead
    if (layer == 0) {
        const float2* pA = (const float2*)xbA;
        const float2* pB = (const float2*)xbB;
        #pragma unroll
        for (int f2 = 0; f2 < F0 / 2; ++f2) { xnA[f2] = pA[f2]; xnB[f2] = pB[f2]; }
    }

    __syncthreads();

    #pragma unroll 1
    for (int t = 0; t < T_STEPS + 3; ++t) {
        if (layer == 0) {
            // ---- phase2: redundant-finish step X = t-1 ----
            if (t >= 1 && t <= T_STEPS) {
                const int sl = (t - 1) & 1;
                const float4 eA = *(const float4*)&ex0[sl][g][u][0];
                const float4 eB = *(const float4*)&ex0[sl][g + 3][u][0];
                cA = fmaf(eA.y, cA, eA.x * eA.z);    // c = sig(f)*c + sig(i)*tanh(g)
                cB = fmaf(eB.y, cB, eB.x * eB.z);
                s_h0[sl][g][u]     = eA.w * tanh_fast(cA);
                s_h0[sl][g + 3][u] = eB.w * tanh_fast(cB);
            }
            // ---- phase1: my gate pre-activation for step t ----
            if (t < T_STEPS) {
                float aA = bias, aB = bias;
                #pragma unroll
                for (int f2 = 0; f2 < F0 / 2; ++f2) {
                    const int f = 2 * f2;
                    const float2 vA = xnA[f2], vB = xnB[f2];
                    aA = fmaf(vA.x, w[f], aA); aA = fmaf(vA.y, w[f + 1], aA);
                    aB = fmaf(vB.x, w[f], aB); aB = fmaf(vB.y, w[f + 1], aB);
                }
                {   // issue x(t+1) loads; latency covered by rest of iteration
                    const int tn = (t + 1 < T_STEPS) ? (t + 1) : (T_STEPS - 1);
                    const float2* pA = (const float2*)(xbA + tn * F0);
                    const float2* pB = (const float2*)(xbB + tn * F0);
                    #pragma unroll
                    for (int f2 = 0; f2 < F0 / 2; ++f2) { xnA[f2] = pA[f2]; xnB[f2] = pB[f2]; }
                }
                // h0(t-1): slot (t-1)&1 == (t+1)&1 — my OWN dup-write from phase2
                const int sl = (t + 1) & 1;
                const float* hpA = &s_h0[sl][g][0];
                const float* hpB = &s_h0[sl][g + 3][0];
                #pragma unroll
                for (int q4 = 0; q4 < HS / 4; ++q4) {
                    const float4 hA = *(const float4*)(hpA + 4 * q4);
                    const float4 hB = *(const float4*)(hpB + 4 * q4);
                    const float eA[4] = {hA.x, hA.y, hA.z, hA.w};
                    const float eB[4] = {hB.x, hB.y, hB.z, hB.w};
                    #pragma unroll
                    for (int e = 0; e < 4; ++e) {
                        const int k = F0 + 4 * q4 + e;
                        aA = fmaf(eA[e], w[k], aA);
                        aB = fmaf(eB[e], w[k], aB);
                    }
                }
                float actA, actB;
                if (q == 2) { actA = tanh_fast(aA);    actB = tanh_fast(aB); }
                else        { actA = sigmoid_fast(aA); actB = sigmoid_fast(aB); }
                ex0[t & 1][g][u][q]     = actA;
                ex0[t & 1][g + 3][u][q] = actB;
            }
        } else {
            // ---- phase2: redundant-finish step X = t-3 ----
            if (t >= 3) {
                const int sl = (t - 3) & 1;
                const float4 eA = *(const float4*)&ex1[sl][g][u][0];
                const float4 eB = *(const float4*)&ex1[sl][g + 3][u][0];
                cA = fmaf(eA.y, cA, eA.x * eA.z);
                cB = fmaf(eB.y, cB, eB.x * eB.z);
                s_h1[sl][g][u]     = eA.w * tanh_fast(cA);
                s_h1[sl][g + 3][u] = eB.w * tanh_fast(cB);
            }
            // ---- phase1: my gate pre-activation for step s = t-2 ----
            if (t >= 2 && t < T_STEPS + 2) {
                float aA = bias, aB = bias;
                // h0(s): slot s&1 == t&1 (published by L0 in region t-1, barrier-protected)
                const int sl0 = t & 1;
                const float* hpA = &s_h0[sl0][g][0];
                const float* hpB = &s_h0[sl0][g + 3][0];
                #pragma unroll
                for (int q4 = 0; q4 < HS / 4; ++q4) {
                    const float4 hA = *(const float4*)(hpA + 4 * q4);
                    const float4 hB = *(const float4*)(hpB + 4 * q4);
                    const float eA[4] = {hA.x, hA.y, hA.z, hA.w};
                    const float eB[4] = {hB.x, hB.y, hB.z, hB.w};
                    #pragma unroll
                    for (int e = 0; e < 4; ++e) {
                        const int k = 4 * q4 + e;
                        aA = fmaf(eA[e], w[k], aA);
                        aB = fmaf(eB[e], w[k], aB);
                    }
                }
                // h1(s-1): slot (s-1)&1 == (t+1)&1 — my OWN dup-write from phase2
                const int sl1 = (t + 1) & 1;
                const float* ppA = &s_h1[sl1][g][0];
                const float* ppB = &s_h1[sl1][g + 3][0];
                #pragma unroll
                for (int q4 = 0; q4 < HS / 4; ++q4) {
                    const float4 hA = *(const float4*)(ppA + 4 * q4);
                    const float4 hB = *(const float4*)(ppB + 4 * q4);
                    const float eA[4] = {hA.x, hA.y, hA.z, hA.w};
                    const float eB[4] = {hB.x, hB.y, hB.z, hB.w};
                    #pragma unroll
                    for (int e = 0; e < 4; ++e) {
                        const int k = HS + 4 * q4 + e;
                        aA = fmaf(eA[e], w[k], aA);
                        aB = fmaf(eB[e], w[k], aB);
                    }
                }
                float actA, actB;
                if (q == 2) { actA = tanh_fast(aA);    actB = tanh_fast(aB); }
                else        { actA = sigmoid_fast(aA); actB = sigmoid_fast(aB); }
                ex1[t & 1][g][u][q]     = actA;   // s&1 == t&1
                ex1[t & 1][g + 3][u][q] = actB;
            }
        }
        __syncthreads();   // the ONE barrier: publish ex (and h0 for L1) per region
    }

    // ---- final FC on h1(T-1), slot (T-1)&1 ----
    if (wid == 7 && lane < 60 && u == 0) {
        const int sl = (T_STEPS - 1) & 1;
        float oA = bfc[0], oB = bfc[0];
        #pragma unroll
        for (int j = 0; j < HS; ++j) {
            oA = fmaf(s_h1[sl][g][j],     wfc[j], oA);
            oB = fmaf(s_h1[sl][g + 3][j], wfc[j], oB);
        }
        out[bgA] = oA;
        if (okB) out[bgBr] = oB;
    }
}

extern "C" void kernel_launch(void* const* d_in, const int* in_sizes, int n_in,
                              void* d_out, int out_size, void* d_ws, size_t ws_size,
                              hipStream_t stream) {
    const float* x    = (const float*)d_in[0];
    const float* wih0 = (const float*)d_in[1];
    const float* whh0 = (const float*)d_in[2];
    const float* bih0 = (const float*)d_in[3];
    const float* bhh0 = (const float*)d_in[4];
    const float* wih1 = (const float*)d_in[5];
    const float* whh1 = (const float*)d_in[6];
    const float* bih1 = (const float*)d_in[7];
    const float* bhh1 = (const float*)d_in[8];
    const float* wfc  = (const float*)d_in[9];
    const float* bfc  = (const float*)d_in[10];
    float* out = (float*)d_out;

    dim3 grid(NBLK), block(512);
    hipLaunchKernelGGL(lstm2_fc_kernel, grid, block, 0, stream,
                       x, wih0, whh0, bih0, bhh0,
                       wih1, whh1, bih1, bhh1, wfc, bfc, out);
}

// Round 4
// 849.788 us; speedup vs baseline: 1.8279x; 1.8279x over previous
//
#include <hip/hip_runtime.h>

#define T_STEPS 512
#define HS 20       // hidden size
#define F0 10       // input features (layer 0)
#define BPB 6       // batches per block: lane-group g handles batches {g, g+3}
#define NB_TOT 4096
#define NBLK ((NB_TOT + BPB - 1) / BPB)   // 683
#define CHK 16                            // x-staging chunk (steps)
#define NCH (T_STEPS / CHK)               // 32 chunks
#define XCHW (CHK * BPB * F0)             // 960 floats per x chunk buffer

__device__ __forceinline__ float sigmoid_fast(float v) {
    return __fdividef(1.f, 1.f + __expf(-v));
}
__device__ __forceinline__ float tanh_fast(float v) {
    return 1.f - __fdividef(2.f, __expf(2.f * v) + 1.f);
}
#define PIN(v) asm volatile("" : "+v"(v))

// Source value for flat x-chunk element i (layout xs[s][b][f], 16*6*10).
__device__ __forceinline__ float stage_ld(const float* __restrict__ x,
                                          int bx, int cc, int i) {
    const int s = i / (BPB * F0);
    const int r = i - s * (BPB * F0);
    const int b = r / F0;
    const int f = r - b * F0;
    int gb = bx * BPB + b; gb = (gb < NB_TOT) ? gb : (NB_TOT - 1);   // clamp batch
    int ts = cc * CHK + s; ts = (ts < T_STEPS) ? ts : (T_STEPS - 1); // clamp step
    return x[(size_t)gb * (T_STEPS * F0) + ts * F0 + f];
}

// Round-2 verified skeleton (4 waves, 2 gates/wave, (256,3)) + two stall fixes:
//  1) x staged per 16-step chunk through LDS (reg-staged: loads issued at region
//     top, ds_write at region bottom -> HBM latency hides under compute; the
//     vmcnt(0) drain hipcc emits at every __syncthreads now has work in flight
//     only once per 16 steps instead of every step).
//  2) ONE barrier per region via redundant finish: both waves of a layer read
//     the packed ex float4 (written by both waves last region), redundantly
//     update identical private c, dup-write h (identical bits - benign), then
//     compute their 2 gates reading h from their OWN just-made write (intra-wave
//     LDS order, no cross-wave wait). L1 runs at 2-step skew so h0 crosses
//     waves only across a barrier.
// All per-accumulator FMA orders / activation math bit-identical to round 2.
__global__ __launch_bounds__(256, 3)
void lstm2_fc_kernel(const float* __restrict__ x,
                     const float* __restrict__ wih0, const float* __restrict__ whh0,
                     const float* __restrict__ bih0, const float* __restrict__ bhh0,
                     const float* __restrict__ wih1, const float* __restrict__ whh1,
                     const float* __restrict__ bih1, const float* __restrict__ bhh1,
                     const float* __restrict__ wfc,  const float* __restrict__ bfc,
                     float* __restrict__ out)
{
    const int tid   = threadIdx.x;
    const int wid   = tid >> 6;
    const int lane  = tid & 63;
    const int g     = (lane / HS) % 3;   // lanes 60..63 shadow group 0 (benign dups)
    const int u     = lane % HS;
    const int layer = wid >> 1;          // 0: waves 0,1 | 1: waves 2,3
    const int half  = wid & 1;           // gate pair: 0 -> {i,f}, 1 -> {g,o}
    const int q0    = 2 * half;
    const int bx    = blockIdx.x;
    const int bgA   = bx * BPB + g;
    const int bgBr  = bx * BPB + g + 3;
    const bool okB  = (bgBr < NB_TOT);

    __shared__ float s_h0[2][BPB][HS];    // h0, slot = t&1 for h0(t)
    __shared__ float s_h1[2][BPB][HS];    // h1, slot = s&1 for h1(s)
    __shared__ float ex0[2][BPB][HS][4];  // packed {sig(i),sig(f),tanh(g),sig(o)} L0
    __shared__ float ex1[2][BPB][HS][4];  // same, L1
    __shared__ float xs[2][XCHW];         // x chunk double buffer

    // ---- stage chunk 0 (issue early; LDS-write below, drains at first barrier)
    const int i3c = (tid + 768 < XCHW) ? (tid + 768) : (XCHW - 1);
    float sv0 = stage_ld(x, bx, 0, tid);
    float sv1 = stage_ld(x, bx, 0, tid + 256);
    float sv2 = stage_ld(x, bx, 0, tid + 512);
    float sv3 = stage_ld(x, bx, 0, i3c);

    for (int i = tid; i < 2 * BPB * HS; i += 256) {
        (&s_h0[0][0][0])[i] = 0.f;
        (&s_h1[0][0][0])[i] = 0.f;
    }

    // ---- per-lane weights: this wave's 2 gate rows ----
    // layer0: w[qh][0..9] = wih0 row, w[qh][10..29] = whh0 row
    // layer1: w[qh][0..19] = wih1 row, w[qh][20..39] = whh1 row
    float w[2][2 * HS], bias[2];
    if (layer == 0) {
        #pragma unroll
        for (int qh = 0; qh < 2; ++qh) {
            const int row = (q0 + qh) * HS + u;
            #pragma unroll
            for (int f = 0; f < F0; ++f) { w[qh][f] = wih0[row * F0 + f]; PIN(w[qh][f]); }
            #pragma unroll
            for (int j = 0; j < HS; ++j) { w[qh][F0 + j] = whh0[row * HS + j]; PIN(w[qh][F0 + j]); }
            bias[qh] = bih0[row] + bhh0[row]; PIN(bias[qh]);
        }
    } else {
        #pragma unroll
        for (int qh = 0; qh < 2; ++qh) {
            const int row = (q0 + qh) * HS + u;
            #pragma unroll
            for (int j = 0; j < HS; ++j) { w[qh][j]      = wih1[row * HS + j]; PIN(w[qh][j]); }
            #pragma unroll
            for (int j = 0; j < HS; ++j) { w[qh][HS + j] = whh1[row * HS + j]; PIN(w[qh][HS + j]); }
            bias[qh] = bih1[row] + bhh1[row]; PIN(bias[qh]);
        }
    }

    float cA = 0.f, cB = 0.f;   // private dup c (identical across the layer's 2 waves)

    xs[0][tid]       = sv0;
    xs[0][tid + 256] = sv1;
    xs[0][tid + 512] = sv2;
    xs[0][i3c]       = sv3;
    __syncthreads();

    #pragma unroll 1
    for (int t = 0; t < T_STEPS + 3; ++t) {
        // ---- issue next-chunk x loads (write to LDS at region bottom) ----
        const bool do_stage = ((t & (CHK - 1)) == 0) && (((t >> 4) + 1) < NCH);
        const int scc = (t >> 4) + 1;
        float tv0, tv1, tv2, tv3;
        if (do_stage) {
            tv0 = stage_ld(x, bx, scc, tid);
            tv1 = stage_ld(x, bx, scc, tid + 256);
            tv2 = stage_ld(x, bx, scc, tid + 512);
            tv3 = stage_ld(x, bx, scc, i3c);
        }

        if (layer == 0) {
            // ---- redundant finish of step t-1 ----
            if (t >= 1 && t <= T_STEPS) {
                const int sl = (t - 1) & 1;
                const float4 eA = *(const float4*)&ex0[sl][g][u][0];
                const float4 eB = *(const float4*)&ex0[sl][g + 3][u][0];
                cA = fmaf(eA.y, cA, eA.x * eA.z);   // c = sig(f)*c + sig(i)*tanh(g)
                cB = fmaf(eB.y, cB, eB.x * eB.z);
                s_h0[sl][g][u]     = eA.w * tanh_fast(cA);   // dup-write, identical bits
                s_h0[sl][g + 3][u] = eB.w * tanh_fast(cB);
            }
            // ---- my 2 gates for step t ----
            if (t < T_STEPS) {
                float a0A = bias[0], a1A = bias[1];
                float a0B = bias[0], a1B = bias[1];
                const float* xr = &xs[(t >> 4) & 1][(t & (CHK - 1)) * (BPB * F0)];
                const float2* xpA = (const float2*)(xr + g * F0);
                const float2* xpB = (const float2*)(xr + (g + 3) * F0);
                #pragma unroll
                for (int f2 = 0; f2 < F0 / 2; ++f2) {
                    const int f = 2 * f2;
                    const float2 vA = xpA[f2], vB = xpB[f2];
                    a0A = fmaf(vA.x, w[0][f], a0A); a0A = fmaf(vA.y, w[0][f + 1], a0A);
                    a1A = fmaf(vA.x, w[1][f], a1A); a1A = fmaf(vA.y, w[1][f + 1], a1A);
                    a0B = fmaf(vB.x, w[0][f], a0B); a0B = fmaf(vB.y, w[0][f + 1], a0B);
                    a1B = fmaf(vB.x, w[1][f], a1B); a1B = fmaf(vB.y, w[1][f + 1], a1B);
                }
                // h0(t-1): slot (t-1)&1 == (t+1)&1 — own dup-write above (same wave)
                const float* hpA = &s_h0[(t + 1) & 1][g][0];
                const float* hpB = &s_h0[(t + 1) & 1][g + 3][0];
                #pragma unroll
                for (int q4 = 0; q4 < HS / 4; ++q4) {
                    const float4 hA = *(const float4*)(hpA + 4 * q4);
                    const float4 hB = *(const float4*)(hpB + 4 * q4);
                    const float eA[4] = {hA.x, hA.y, hA.z, hA.w};
                    const float eB[4] = {hB.x, hB.y, hB.z, hB.w};
                    #pragma unroll
                    for (int e = 0; e < 4; ++e) {
                        const int k = F0 + 4 * q4 + e;
                        a0A = fmaf(eA[e], w[0][k], a0A);  a0B = fmaf(eB[e], w[0][k], a0B);
                        a1A = fmaf(eA[e], w[1][k], a1A);  a1B = fmaf(eB[e], w[1][k], a1B);
                    }
                }
                float act0A, act1A, act0B, act1B;
                if (half == 0) {
                    act0A = sigmoid_fast(a0A); act1A = sigmoid_fast(a1A);
                    act0B = sigmoid_fast(a0B); act1B = sigmoid_fast(a1B);
                } else {
                    act0A = tanh_fast(a0A);    act1A = sigmoid_fast(a1A);
                    act0B = tanh_fast(a0B);    act1B = sigmoid_fast(a1B);
                }
                *(float2*)&ex0[t & 1][g][u][q0]     = make_float2(act0A, act1A);
                *(float2*)&ex0[t & 1][g + 3][u][q0] = make_float2(act0B, act1B);
            }
        } else {
            // ---- redundant finish of step t-3 ----
            if (t >= 3) {
                const int sl = (t - 3) & 1;
                const float4 eA = *(const float4*)&ex1[sl][g][u][0];
                const float4 eB = *(const float4*)&ex1[sl][g + 3][u][0];
                cA = fmaf(eA.y, cA, eA.x * eA.z);
                cB = fmaf(eB.y, cB, eB.x * eB.z);
                s_h1[sl][g][u]     = eA.w * tanh_fast(cA);
                s_h1[sl][g + 3][u] = eB.w * tanh_fast(cB);
            }
            // ---- my 2 gates for step s = t-2 ----
            if (t >= 2 && t < T_STEPS + 2) {
                float a0A = bias[0], a1A = bias[1];
                float a0B = bias[0], a1B = bias[1];
                // h0(s): slot s&1 == t&1, published by L0 at region t-1 (barrier)
                const float* hpA = &s_h0[t & 1][g][0];
                const float* hpB = &s_h0[t & 1][g + 3][0];
                #pragma unroll
                for (int q4 = 0; q4 < HS / 4; ++q4) {
                    const float4 hA = *(const float4*)(hpA + 4 * q4);
                    const float4 hB = *(const float4*)(hpB + 4 * q4);
                    const float eA[4] = {hA.x, hA.y, hA.z, hA.w};
                    const float eB[4] = {hB.x, hB.y, hB.z, hB.w};
                    #pragma unroll
                    for (int e = 0; e < 4; ++e) {
                        const int k = 4 * q4 + e;
                        a0A = fmaf(eA[e], w[0][k], a0A);  a0B = fmaf(eB[e], w[0][k], a0B);
                        a1A = fmaf(eA[e], w[1][k], a1A);  a1B = fmaf(eB[e], w[1][k], a1B);
                    }
                }
                // h1(s-1): slot (s-1)&1 == (t+1)&1 — own dup-write above (same wave)
                const float* ppA = &s_h1[(t + 1) & 1][g][0];
                const float* ppB = &s_h1[(t + 1) & 1][g + 3][0];
                #pragma unroll
                for (int q4 = 0; q4 < HS / 4; ++q4) {
                    const float4 hA = *(const float4*)(ppA + 4 * q4);
                    const float4 hB = *(const float4*)(ppB + 4 * q4);
                    const float eA[4] = {hA.x, hA.y, hA.z, hA.w};
                    const float eB[4] = {hB.x, hB.y, hB.z, hB.w};
                    #pragma unroll
                    for (int e = 0; e < 4; ++e) {
                        const int k = HS + 4 * q4 + e;
                        a0A = fmaf(eA[e], w[0][k], a0A);  a0B = fmaf(eB[e], w[0][k], a0B);
                        a1A = fmaf(eA[e], w[1][k], a1A);  a1B = fmaf(eB[e], w[1][k], a1B);
                    }
                }
                float act0A, act1A, act0B, act1B;
                if (half == 0) {
                    act0A = sigmoid_fast(a0A); act1A = sigmoid_fast(a1A);
                    act0B = sigmoid_fast(a0B); act1B = sigmoid_fast(a1B);
                } else {
                    act0A = tanh_fast(a0A);    act1A = sigmoid_fast(a1A);
                    act0B = tanh_fast(a0B);    act1B = sigmoid_fast(a1B);
                }
                *(float2*)&ex1[t & 1][g][u][q0]     = make_float2(act0A, act1A);  // s&1 == t&1
                *(float2*)&ex1[t & 1][g + 3][u][q0] = make_float2(act0B, act1B);
            }
        }

        // ---- LDS-write staged x (loads have had ~a full region to land) ----
        if (do_stage) {
            float* xw = &xs[scc & 1][0];
            xw[tid]       = tv0;
            xw[tid + 256] = tv1;
            xw[tid + 512] = tv2;
            xw[i3c]       = tv3;
        }
        __syncthreads();   // the ONE barrier per region
    }

    // ---- final FC on h1(T-1), slot (T-1)&1 ----
    if (wid == 3 && lane < 60 && u == 0) {
        const int sl = (T_STEPS - 1) & 1;
        float oA = bfc[0], oB = bfc[0];
        #pragma unroll
        for (int j = 0; j < HS; ++j) {
            oA = fmaf(s_h1[sl][g][j],     wfc[j], oA);
            oB = fmaf(s_h1[sl][g + 3][j], wfc[j], oB);
        }
        out[bgA] = oA;
        if (okB) out[bgBr] = oB;
    }
}

extern "C" void kernel_launch(void* const* d_in, const int* in_sizes, int n_in,
                              void* d_out, int out_size, void* d_ws, size_t ws_size,
                              hipStream_t stream) {
    const float* x    = (const float*)d_in[0];
    const float* wih0 = (const float*)d_in[1];
    const float* whh0 = (const float*)d_in[2];
    const float* bih0 = (const float*)d_in[3];
    const float* bhh0 = (const float*)d_in[4];
    const float* wih1 = (const float*)d_in[5];
    const float* whh1 = (const float*)d_in[6];
    const float* bih1 = (const float*)d_in[7];
    const float* bhh1 = (const float*)d_in[8];
    const float* wfc  = (const float*)d_in[9];
    const float* bfc  = (const float*)d_in[10];
    float* out = (float*)d_out;

    dim3 grid(NBLK), block(256);
    hipLaunchKernelGGL(lstm2_fc_kernel, grid, block, 0, stream,
                       x, wih0, whh0, bih0, bhh0,
                       wih1, whh1, bih1, bhh1, wfc, bfc, out);
}

// Round 5
// 780.750 us; speedup vs baseline: 1.9895x; 1.0884x over previous
//
#include <hip/hip_runtime.h>

#define T_STEPS 512
#define HS 20       // hidden size
#define F0 10       // input features (layer 0)
#define BPB 6       // batches per block: lane-group g handles batches {g, g+3}
#define NB_TOT 4096
#define NBLK ((NB_TOT + BPB - 1) / BPB)   // 683
#define CHK 16                            // x-staging chunk (steps)
#define NCH (T_STEPS / CHK)               // 32 chunks
#define XCHW (CHK * BPB * F0)             // 960 floats per x chunk buffer

__device__ __forceinline__ float sigmoid_fast(float v) {
    return __fdividef(1.f, 1.f + __expf(-v));
}
__device__ __forceinline__ float tanh_fast(float v) {
    return 1.f - __fdividef(2.f, __expf(2.f * v) + 1.f);
}
#define PIN(v) asm volatile("" : "+v"(v))

// Source value for flat x-chunk element i (layout xs[s][b][f], 16*6*10).
__device__ __forceinline__ float stage_ld(const float* __restrict__ x,
                                          int bx, int cc, int i) {
    const int s = i / (BPB * F0);
    const int r = i - s * (BPB * F0);
    const int b = r / F0;
    const int f = r - b * F0;
    int gb = bx * BPB + b; gb = (gb < NB_TOT) ? gb : (NB_TOT - 1);   // clamp batch
    int ts = cc * CHK + s; ts = (ts < T_STEPS) ? ts : (T_STEPS - 1); // clamp step
    return x[(size_t)gb * (T_STEPS * F0) + ts * F0 + f];
}

// R2 two-phase skeleton (4 waves, 2 gates/wave, (256,3)) + three isolated fixes:
//  1) x staged per 16-step chunk through LDS: steady-state steps carry NO
//     in-flight global loads, so the vmcnt(0) drain hipcc emits before every
//     __syncthreads is free in 15/16 regions. Stage loads issue at region top,
//     ds_write right before the mid barrier (~phase1 of latency cover, 1/16 freq).
//  2) chain split: each gate pre-act = (bias + x-part) + (h-part from 0),
//     dependent-FMA chain 30->~21 (L0) / 40->~21 (L1). FP-order change is
//     evidenced safe (R0<->R2 reordered accumulation, both passed absmax 0.0).
//  3) batch-split finish: half-wave0 finishes batch A, half-wave1 batch B.
//     Both waves work in phase2; each carries ONE c; finish LDS ops/wave halved
//     vs R2's single-finisher (R4's 4-wave redundant finish caused 10x bank
//     conflicts - this keeps finish traffic at R2 level, balanced).
__global__ __launch_bounds__(256, 3)
void lstm2_fc_kernel(const float* __restrict__ x,
                     const float* __restrict__ wih0, const float* __restrict__ whh0,
                     const float* __restrict__ bih0, const float* __restrict__ bhh0,
                     const float* __restrict__ wih1, const float* __restrict__ whh1,
                     const float* __restrict__ bih1, const float* __restrict__ bhh1,
                     const float* __restrict__ wfc,  const float* __restrict__ bfc,
                     float* __restrict__ out)
{
    const int tid   = threadIdx.x;
    const int wid   = tid >> 6;
    const int lane  = tid & 63;
    const int g     = (lane / HS) % 3;   // lanes 60..63 shadow group 0 (benign dups)
    const int u     = lane % HS;
    const int layer = wid >> 1;          // 0: waves 0,1 | 1: waves 2,3
    const int half  = wid & 1;           // gate pair: 0 -> {i,f}, 1 -> {g,o}
    const int q0    = 2 * half;
    const int gfin  = (half == 0) ? g : (g + 3);   // batch this wave finishes
    const int bx    = blockIdx.x;
    const int bgA   = bx * BPB + g;
    const int bgBr  = bx * BPB + g + 3;
    const bool okB  = (bgBr < NB_TOT);

    __shared__ float s_h0[2][BPB][HS];    // h0, slot = t&1 for h0(t)
    __shared__ float s_h1[2][BPB][HS];    // h1, slot = s&1 for h1(s)
    __shared__ float ex0[BPB][HS][4];     // packed {sig(i),sig(f),tanh(g),sig(o)} L0
    __shared__ float ex1[BPB][HS][4];     // same, L1 (single buffer: 2 barriers/step)
    __shared__ float xs[2][XCHW];         // x chunk double buffer

    // ---- stage chunk 0 (issue early; weights-load latency covers it) ----
    const bool st3 = (tid < XCHW - 768);          // tid<192: waves 0-2, wave-uniform
    float sv0 = stage_ld(x, bx, 0, tid);
    float sv1 = stage_ld(x, bx, 0, tid + 256);
    float sv2 = stage_ld(x, bx, 0, tid + 512);
    float sv3 = st3 ? stage_ld(x, bx, 0, tid + 768) : 0.f;

    for (int i = tid; i < 2 * BPB * HS; i += 256) {
        (&s_h0[0][0][0])[i] = 0.f;
        (&s_h1[0][0][0])[i] = 0.f;
    }

    // ---- per-lane weights: this wave's 2 gate rows ----
    // layer0: w[qh][0..9] = wih0 row, w[qh][10..29] = whh0 row
    // layer1: w[qh][0..19] = wih1 row, w[qh][20..39] = whh1 row
    float w[2][2 * HS], bias[2];
    if (layer == 0) {
        #pragma unroll
        for (int qh = 0; qh < 2; ++qh) {
            const int row = (q0 + qh) * HS + u;
            #pragma unroll
            for (int f = 0; f < F0; ++f) { w[qh][f] = wih0[row * F0 + f]; PIN(w[qh][f]); }
            #pragma unroll
            for (int j = 0; j < HS; ++j) { w[qh][F0 + j] = whh0[row * HS + j]; PIN(w[qh][F0 + j]); }
            bias[qh] = bih0[row] + bhh0[row]; PIN(bias[qh]);
        }
    } else {
        #pragma unroll
        for (int qh = 0; qh < 2; ++qh) {
            const int row = (q0 + qh) * HS + u;
            #pragma unroll
            for (int j = 0; j < HS; ++j) { w[qh][j]      = wih1[row * HS + j]; PIN(w[qh][j]); }
            #pragma unroll
            for (int j = 0; j < HS; ++j) { w[qh][HS + j] = whh1[row * HS + j]; PIN(w[qh][HS + j]); }
            bias[qh] = bih1[row] + bhh1[row]; PIN(bias[qh]);
        }
    }

    float cc = 0.f;   // the ONE cell state this wave finishes (batch gfin)

    xs[0][tid]       = sv0;
    xs[0][tid + 256] = sv1;
    xs[0][tid + 512] = sv2;
    if (st3) xs[0][tid + 768] = sv3;
    __syncthreads();

    #pragma unroll 1
    for (int t = 0; t <= T_STEPS; ++t) {
        // ---- issue next-chunk x loads (ds_write just before mid barrier) ----
        const bool do_stage = ((t & (CHK - 1)) == 0) && (((t >> 4) + 1) < NCH);
        const int scc = (t >> 4) + 1;
        float tv0, tv1, tv2, tv3;
        if (do_stage) {
            tv0 = stage_ld(x, bx, scc, tid);
            tv1 = stage_ld(x, bx, scc, tid + 256);
            tv2 = stage_ld(x, bx, scc, tid + 512);
            tv3 = st3 ? stage_ld(x, bx, scc, tid + 768) : 0.f;
        }

        // ================= phase 1: gate pre-activations =================
        if (layer == 0) {
            if (t < T_STEPS) {
                // x-partials start from bias; h-partials from 0 (chain split)
                float xa0A = bias[0], xa1A = bias[1];
                float xa0B = bias[0], xa1B = bias[1];
                float ha0A = 0.f, ha1A = 0.f, ha0B = 0.f, ha1B = 0.f;
                const float* xr = &xs[(t >> 4) & 1][(t & (CHK - 1)) * (BPB * F0)];
                const float2* xpA = (const float2*)(xr + g * F0);
                const float2* xpB = (const float2*)(xr + (g + 3) * F0);
                #pragma unroll
                for (int f2 = 0; f2 < F0 / 2; ++f2) {
                    const int f = 2 * f2;
                    const float2 vA = xpA[f2], vB = xpB[f2];
                    xa0A = fmaf(vA.x, w[0][f], xa0A); xa0A = fmaf(vA.y, w[0][f + 1], xa0A);
                    xa1A = fmaf(vA.x, w[1][f], xa1A); xa1A = fmaf(vA.y, w[1][f + 1], xa1A);
                    xa0B = fmaf(vB.x, w[0][f], xa0B); xa0B = fmaf(vB.y, w[0][f + 1], xa0B);
                    xa1B = fmaf(vB.x, w[1][f], xa1B); xa1B = fmaf(vB.y, w[1][f + 1], xa1B);
                }
                // h0(t-1): slot (t-1)&1 == (t+1)&1
                const float* hpA = &s_h0[(t + 1) & 1][g][0];
                const float* hpB = &s_h0[(t + 1) & 1][g + 3][0];
                #pragma unroll
                for (int q4 = 0; q4 < HS / 4; ++q4) {
                    const float4 hA = *(const float4*)(hpA + 4 * q4);
                    const float4 hB = *(const float4*)(hpB + 4 * q4);
                    const float eA[4] = {hA.x, hA.y, hA.z, hA.w};
                    const float eB[4] = {hB.x, hB.y, hB.z, hB.w};
                    #pragma unroll
                    for (int e = 0; e < 4; ++e) {
                        const int k = F0 + 4 * q4 + e;
                        ha0A = fmaf(eA[e], w[0][k], ha0A);  ha0B = fmaf(eB[e], w[0][k], ha0B);
                        ha1A = fmaf(eA[e], w[1][k], ha1A);  ha1B = fmaf(eB[e], w[1][k], ha1B);
                    }
                }
                const float a0A = xa0A + ha0A, a1A = xa1A + ha1A;
                const float a0B = xa0B + ha0B, a1B = xa1B + ha1B;
                float act0A, act1A, act0B, act1B;
                if (half == 0) {
                    act0A = sigmoid_fast(a0A); act1A = sigmoid_fast(a1A);
                    act0B = sigmoid_fast(a0B); act1B = sigmoid_fast(a1B);
                } else {
                    act0A = tanh_fast(a0A);    act1A = sigmoid_fast(a1A);
                    act0B = tanh_fast(a0B);    act1B = sigmoid_fast(a1B);
                }
                *(float2*)&ex0[g][u][q0]     = make_float2(act0A, act1A);
                *(float2*)&ex0[g + 3][u][q0] = make_float2(act0B, act1B);
            }
        } else {
            if (t >= 1) {
                // layer1 computes step s = t-1
                float xa0A = bias[0], xa1A = bias[1];   // h0-partials (from bias)
                float xa0B = bias[0], xa1B = bias[1];
                float ha0A = 0.f, ha1A = 0.f, ha0B = 0.f, ha1B = 0.f;  // h1-partials
                // h0(s): slot (t-1)&1
                const float* hpA = &s_h0[(t - 1) & 1][g][0];
                const float* hpB = &s_h0[(t - 1) & 1][g + 3][0];
                #pragma unroll
                for (int q4 = 0; q4 < HS / 4; ++q4) {
                    const float4 hA = *(const float4*)(hpA + 4 * q4);
                    const float4 hB = *(const float4*)(hpB + 4 * q4);
                    const float eA[4] = {hA.x, hA.y, hA.z, hA.w};
                    const float eB[4] = {hB.x, hB.y, hB.z, hB.w};
                    #pragma unroll
                    for (int e = 0; e < 4; ++e) {
                        const int k = 4 * q4 + e;
                        xa0A = fmaf(eA[e], w[0][k], xa0A);  xa0B = fmaf(eB[e], w[0][k], xa0B);
                        xa1A = fmaf(eA[e], w[1][k], xa1A);  xa1B = fmaf(eB[e], w[1][k], xa1B);
                    }
                }
                // h1(s-1): slot (s-1)&1 == t&1
                const float* ppA = &s_h1[t & 1][g][0];
                const float* ppB = &s_h1[t & 1][g + 3][0];
                #pragma unroll
                for (int q4 = 0; q4 < HS / 4; ++q4) {
                    const float4 hA = *(const float4*)(ppA + 4 * q4);
                    const float4 hB = *(const float4*)(ppB + 4 * q4);
                    const float eA[4] = {hA.x, hA.y, hA.z, hA.w};
                    const float eB[4] = {hB.x, hB.y, hB.z, hB.w};
                    #pragma unroll
                    for (int e = 0; e < 4; ++e) {
                        const int k = HS + 4 * q4 + e;
                        ha0A = fmaf(eA[e], w[0][k], ha0A);  ha0B = fmaf(eB[e], w[0][k], ha0B);
                        ha1A = fmaf(eA[e], w[1][k], ha1A);  ha1B = fmaf(eB[e], w[1][k], ha1B);
                    }
                }
                const float a0A = xa0A + ha0A, a1A = xa1A + ha1A;
                const float a0B = xa0B + ha0B, a1B = xa1B + ha1B;
                float act0A, act1A, act0B, act1B;
                if (half == 0) {
                    act0A = sigmoid_fast(a0A); act1A = sigmoid_fast(a1A);
                    act0B = sigmoid_fast(a0B); act1B = sigmoid_fast(a1B);
                } else {
                    act0A = tanh_fast(a0A);    act1A = sigmoid_fast(a1A);
                    act0B = tanh_fast(a0B);    act1B = sigmoid_fast(a1B);
                }
                *(float2*)&ex1[g][u][q0]     = make_float2(act0A, act1A);
                *(float2*)&ex1[g + 3][u][q0] = make_float2(act0B, act1B);
            }
        }

        // ---- LDS-write staged x (loads had ~phase1 to land; 1/16 regions) ----
        if (do_stage) {
            float* xw = &xs[scc & 1][0];
            xw[tid]       = tv0;
            xw[tid + 256] = tv1;
            xw[tid + 512] = tv2;
            if (st3) xw[tid + 768] = tv3;
        }
        __syncthreads();   // publish ex (and staged x)

        // ===== phase 2: batch-split finish (each wave finishes ONE batch) =====
        if (layer == 0) {
            if (t < T_STEPS) {
                const float4 e = *(const float4*)&ex0[gfin][u][0];
                cc = fmaf(e.y, cc, e.x * e.z);     // c = sig(f)*c + sig(i)*tanh(g)
                s_h0[t & 1][gfin][u] = e.w * tanh_fast(cc);
            }
        } else {
            if (t >= 1) {
                const float4 e = *(const float4*)&ex1[gfin][u][0];
                cc = fmaf(e.y, cc, e.x * e.z);
                s_h1[(t - 1) & 1][gfin][u] = e.w * tanh_fast(cc);
            }
        }
        __syncthreads();   // publish h; WAR-protect ex and h slots
    }

    // ---- final FC on h1(T-1), slot (T-1)&1 ----
    if (wid == 3 && lane < 60 && u == 0) {
        const int sl = (T_STEPS - 1) & 1;
        float oA = bfc[0], oB = bfc[0];
        #pragma unroll
        for (int j = 0; j < HS; ++j) {
            oA = fmaf(s_h1[sl][g][j],     wfc[j], oA);
            oB = fmaf(s_h1[sl][g + 3][j], wfc[j], oB);
        }
        out[bgA] = oA;
        if (okB) out[bgBr] = oB;
    }
}

extern "C" void kernel_launch(void* const* d_in, const int* in_sizes, int n_in,
                              void* d_out, int out_size, void* d_ws, size_t ws_size,
                              hipStream_t stream) {
    const float* x    = (const float*)d_in[0];
    const float* wih0 = (const float*)d_in[1];
    const float* whh0 = (const float*)d_in[2];
    const float* bih0 = (const float*)d_in[3];
    const float* bhh0 = (const float*)d_in[4];
    const float* wih1 = (const float*)d_in[5];
    const float* whh1 = (const float*)d_in[6];
    const float* bih1 = (const float*)d_in[7];
    const float* bhh1 = (const float*)d_in[8];
    const float* wfc  = (const float*)d_in[9];
    const float* bfc  = (const float*)d_in[10];
    float* out = (float*)d_out;

    dim3 grid(NBLK), block(256);
    hipLaunchKernelGGL(lstm2_fc_kernel, grid, block, 0, stream,
                       x, wih0, whh0, bih0, bhh0,
                       wih1, whh1, bih1, bhh1, wfc, bfc, out);
}

// Round 6
// 763.492 us; speedup vs baseline: 2.0345x; 1.0226x over previous
//
#include <hip/hip_runtime.h>

#define T_STEPS 512
#define HS 20       // hidden size
#define F0 10       // input features (layer 0)
#define BPB 6       // batches per block: lane-group g handles batches {g, g+3}
#define NB_TOT 4096
#define NBLK ((NB_TOT + BPB - 1) / BPB)   // 683

typedef float v2f __attribute__((ext_vector_type(2)));

__device__ __forceinline__ float sigmoid_fast(float v) {
    return __fdividef(1.f, 1.f + __expf(-v));
}
__device__ __forceinline__ float tanh_fast(float v) {
    return 1.f - __fdividef(2.f, __expf(2.f * v) + 1.f);
}
#define PIN(v) asm volatile("" : "+v"(v))

// v_pk_fma_f32: acc.{lo,hi} += wpair.{lo,hi} * broadcast(sel half of s).
// op_sel   selects the source half feeding the LOW lane of the packed op,
// op_sel_hi selects the source half feeding the HIGH lane.
//   LO: lo = wp.lo*s.lo + acc.lo ; hi = wp.hi*s.lo + acc.hi
#define PK_FMA_LO(acc, wp, s) \
    asm("v_pk_fma_f32 %0, %1, %2, %0 op_sel:[0,0,0] op_sel_hi:[1,0,1]" \
        : "+v"(acc) : "v"(wp), "v"(s))
//   HI: lo = wp.lo*s.hi + acc.lo ; hi = wp.hi*s.hi + acc.hi
#define PK_FMA_HI(acc, wp, s) \
    asm("v_pk_fma_f32 %0, %1, %2, %0 op_sel:[0,1,0] op_sel_hi:[1,1,1]" \
        : "+v"(acc) : "v"(wp), "v"(s))

// R2 verified skeleton (4 waves, 2 gates/wave, (256,3), 2 barriers/step, 735us)
// with ONE change: gate-pair FMAs packed into v_pk_fma_f32.
//   wp[j] = {w_gateq0[j], w_gateq0+1[j]}  (same 80 VGPRs, interleaved)
//   acc   = {a_q0, a_q0+1}; the shared x/h scalar is broadcast via op_sel from
//   its natural float2/float4 register half -> zero extra movs.
// Per-accumulator operand sequences are IDENTICAL to R2's fmaf chains
// (bias -> x ascending -> h ascending) -> bit-identical results.
// FMA instructions per wave-step: L0 120->60, L1 160->80. If packed FP32 is
// full-rate on gfx950 this halves the dominant VALU issue cost.
__global__ __launch_bounds__(256, 3)
void lstm2_fc_kernel(const float* __restrict__ x,
                     const float* __restrict__ wih0, const float* __restrict__ whh0,
                     const float* __restrict__ bih0, const float* __restrict__ bhh0,
                     const float* __restrict__ wih1, const float* __restrict__ whh1,
                     const float* __restrict__ bih1, const float* __restrict__ bhh1,
                     const float* __restrict__ wfc,  const float* __restrict__ bfc,
                     float* __restrict__ out)
{
    const int tid   = threadIdx.x;
    const int wid   = tid >> 6;
    const int lane  = tid & 63;
    const int g     = (lane / HS) % 3;   // lanes 60..63 shadow group 0 (benign dups)
    const int u     = lane % HS;
    const int layer = wid >> 1;          // 0: waves 0,1 | 1: waves 2,3
    const int half  = wid & 1;           // gate pair: 0 -> {i,f}, 1 -> {g,o}
    const int q0    = 2 * half;
    const int bgA   = blockIdx.x * BPB + g;
    const int bgBr  = blockIdx.x * BPB + g + 3;
    const bool okB  = (bgBr < NB_TOT);
    const int bgB   = okB ? bgBr : (NB_TOT - 1);   // clamp reads

    __shared__ float s_h0[2][BPB][HS];  // h0 double buffer, slot = t&1 for h0(t)
    __shared__ float s_h1[2][BPB][HS];  // h1 double buffer, slot = s&1 for h1(s)
    __shared__ float ex0[BPB][HS][2];   // {sig(i), sig(f)} layer0, written by wave0
    __shared__ float ex1[BPB][HS][2];   // {sig(i), sig(f)} layer1, written by wave2

    for (int i = tid; i < 2 * BPB * HS; i += 256) {
        (&s_h0[0][0][0])[i] = 0.f;
        (&s_h1[0][0][0])[i] = 0.f;
    }

    // ---- per-lane packed weights: this wave's 2 gate rows, interleaved ----
    // layer0: wp[0..9] = {wih0 r0, wih0 r1}, wp[10..29] = {whh0 r0, whh0 r1}
    // layer1: wp[0..19] = {wih1 r0, wih1 r1}, wp[20..39] = {whh1 r0, whh1 r1}
    v2f wp[2 * HS], bias2;
    {
        const int r0 = q0 * HS + u, r1 = (q0 + 1) * HS + u;
        if (layer == 0) {
            #pragma unroll
            for (int f = 0; f < F0; ++f) {
                v2f t; t.x = wih0[r0 * F0 + f]; t.y = wih0[r1 * F0 + f];
                wp[f] = t; PIN(wp[f]);
            }
            #pragma unroll
            for (int j = 0; j < HS; ++j) {
                v2f t; t.x = whh0[r0 * HS + j]; t.y = whh0[r1 * HS + j];
                wp[F0 + j] = t; PIN(wp[F0 + j]);
            }
            bias2.x = bih0[r0] + bhh0[r0];
            bias2.y = bih0[r1] + bhh0[r1]; PIN(bias2);
        } else {
            #pragma unroll
            for (int j = 0; j < HS; ++j) {
                v2f t; t.x = wih1[r0 * HS + j]; t.y = wih1[r1 * HS + j];
                wp[j] = t; PIN(wp[j]);
            }
            #pragma unroll
            for (int j = 0; j < HS; ++j) {
                v2f t; t.x = whh1[r0 * HS + j]; t.y = whh1[r1 * HS + j];
                wp[HS + j] = t; PIN(wp[HS + j]);
            }
            bias2.x = bih1[r0] + bhh1[r0];
            bias2.y = bih1[r1] + bhh1[r1]; PIN(bias2);
        }
    }

    float cA = 0.f, cB = 0.f;            // carried by finisher waves only
    const float* xbA = x + (size_t)bgA * (T_STEPS * F0);
    const float* xbB = x + (size_t)bgB * (T_STEPS * F0);

    // layer0 waves: x(t) prefetched one step ahead
    v2f xnA[F0 / 2], xnB[F0 / 2];
    if (layer == 0) {
        const v2f* pA = (const v2f*)xbA;
        const v2f* pB = (const v2f*)xbB;
        #pragma unroll
        for (int f2 = 0; f2 < F0 / 2; ++f2) { xnA[f2] = pA[f2]; xnB[f2] = pB[f2]; }
    }

    __syncthreads();

    float tgA = 0.f, soA = 0.f, tgB = 0.f, soB = 0.f;  // finisher tanh(g), sig(o)

    #pragma unroll 1
    for (int t = 0; t <= T_STEPS; ++t) {
        // ================= phase 1: gate pre-activations =================
        if (layer == 0) {
            if (t < T_STEPS) {
                v2f accA = bias2, accB = bias2;
                // x-part first (same accumulation order as R2)
                #pragma unroll
                for (int f2 = 0; f2 < F0 / 2; ++f2) {
                    const int f = 2 * f2;
                    PK_FMA_LO(accA, wp[f],     xnA[f2]);
                    PK_FMA_HI(accA, wp[f + 1], xnA[f2]);
                    PK_FMA_LO(accB, wp[f],     xnB[f2]);
                    PK_FMA_HI(accB, wp[f + 1], xnB[f2]);
                }
                {   // issue x(t+1) loads; latency covered by rest of iteration
                    const int tn = (t + 1 < T_STEPS) ? (t + 1) : (T_STEPS - 1);
                    const v2f* pA = (const v2f*)(xbA + tn * F0);
                    const v2f* pB = (const v2f*)(xbB + tn * F0);
                    #pragma unroll
                    for (int f2 = 0; f2 < F0 / 2; ++f2) { xnA[f2] = pA[f2]; xnB[f2] = pB[f2]; }
                }
                // h0(t-1) part, slot (t-1)&1 == (t+1)&1
                const float* hpA = &s_h0[(t + 1) & 1][g][0];
                const float* hpB = &s_h0[(t + 1) & 1][g + 3][0];
                #pragma unroll
                for (int q4 = 0; q4 < HS / 4; ++q4) {
                    float4 hA = *(const float4*)(hpA + 4 * q4);
                    float4 hB = *(const float4*)(hpB + 4 * q4);
                    const v2f hA01 = *(v2f*)&hA.x, hA23 = *(v2f*)&hA.z;
                    const v2f hB01 = *(v2f*)&hB.x, hB23 = *(v2f*)&hB.z;
                    const int k = F0 + 4 * q4;
                    PK_FMA_LO(accA, wp[k],     hA01);
                    PK_FMA_HI(accA, wp[k + 1], hA01);
                    PK_FMA_LO(accA, wp[k + 2], hA23);
                    PK_FMA_HI(accA, wp[k + 3], hA23);
                    PK_FMA_LO(accB, wp[k],     hB01);
                    PK_FMA_HI(accB, wp[k + 1], hB01);
                    PK_FMA_LO(accB, wp[k + 2], hB23);
                    PK_FMA_HI(accB, wp[k + 3], hB23);
                }
                if (half == 0) {
                    *(float2*)&ex0[g][u][0]     = make_float2(sigmoid_fast(accA.x), sigmoid_fast(accA.y));
                    *(float2*)&ex0[g + 3][u][0] = make_float2(sigmoid_fast(accB.x), sigmoid_fast(accB.y));
                } else {
                    tgA = tanh_fast(accA.x); soA = sigmoid_fast(accA.y);
                    tgB = tanh_fast(accB.x); soB = sigmoid_fast(accB.y);
                }
            }
        } else {
            if (t >= 1) {
                // layer1 computes step s = t-1
                v2f accA = bias2, accB = bias2;
                // h0(s) part, slot (t-1)&1
                const float* hpA = &s_h0[(t - 1) & 1][g][0];
                const float* hpB = &s_h0[(t - 1) & 1][g + 3][0];
                #pragma unroll
                for (int q4 = 0; q4 < HS / 4; ++q4) {
                    float4 hA = *(const float4*)(hpA + 4 * q4);
                    float4 hB = *(const float4*)(hpB + 4 * q4);
                    const v2f hA01 = *(v2f*)&hA.x, hA23 = *(v2f*)&hA.z;
                    const v2f hB01 = *(v2f*)&hB.x, hB23 = *(v2f*)&hB.z;
                    const int k = 4 * q4;
                    PK_FMA_LO(accA, wp[k],     hA01);
                    PK_FMA_HI(accA, wp[k + 1], hA01);
                    PK_FMA_LO(accA, wp[k + 2], hA23);
                    PK_FMA_HI(accA, wp[k + 3], hA23);
                    PK_FMA_LO(accB, wp[k],     hB01);
                    PK_FMA_HI(accB, wp[k + 1], hB01);
                    PK_FMA_LO(accB, wp[k + 2], hB23);
                    PK_FMA_HI(accB, wp[k + 3], hB23);
                }
                // h1(s-1) part, slot (s-1)&1 == t&1
                const float* ppA = &s_h1[t & 1][g][0];
                const float* ppB = &s_h1[t & 1][g + 3][0];
                #pragma unroll
                for (int q4 = 0; q4 < HS / 4; ++q4) {
                    float4 hA = *(const float4*)(ppA + 4 * q4);
                    float4 hB = *(const float4*)(ppB + 4 * q4);
                    const v2f hA01 = *(v2f*)&hA.x, hA23 = *(v2f*)&hA.z;
                    const v2f hB01 = *(v2f*)&hB.x, hB23 = *(v2f*)&hB.z;
                    const int k = HS + 4 * q4;
                    PK_FMA_LO(accA, wp[k],     hA01);
                    PK_FMA_HI(accA, wp[k + 1], hA01);
                    PK_FMA_LO(accA, wp[k + 2], hA23);
                    PK_FMA_HI(accA, wp[k + 3], hA23);
                    PK_FMA_LO(accB, wp[k],     hB01);
                    PK_FMA_HI(accB, wp[k + 1], hB01);
                    PK_FMA_LO(accB, wp[k + 2], hB23);
                    PK_FMA_HI(accB, wp[k + 3], hB23);
                }
                if (half == 0) {
                    *(float2*)&ex1[g][u][0]     = make_float2(sigmoid_fast(accA.x), sigmoid_fast(accA.y));
                    *(float2*)&ex1[g + 3][u][0] = make_float2(sigmoid_fast(accB.x), sigmoid_fast(accB.y));
                } else {
                    tgA = tanh_fast(accA.x); soA = sigmoid_fast(accA.y);
                    tgB = tanh_fast(accB.x); soB = sigmoid_fast(accB.y);
                }
            }
        }
        __syncthreads();   // publish sig(i),sig(f) halves

        // ================= phase 2: finishers update c, write h =================
        if (half == 1) {
            const bool act = (layer == 0) ? (t < T_STEPS) : (t >= 1);
            if (act) {
                float2 sifA, sifB;
                if (layer == 0) {
                    sifA = *(const float2*)&ex0[g][u][0];
                    sifB = *(const float2*)&ex0[g + 3][u][0];
                } else {
                    sifA = *(const float2*)&ex1[g][u][0];
                    sifB = *(const float2*)&ex1[g + 3][u][0];
                }
                cA = fmaf(sifA.y, cA, sifA.x * tgA);   // c = sig(f)*c + sig(i)*tanh(g)
                cB = fmaf(sifB.y, cB, sifB.x * tgB);
                const float hA = soA * tanh_fast(cA);
                const float hB = soB * tanh_fast(cB);
                if (layer == 0) {
                    s_h0[t & 1][g][u]       = hA;
                    s_h0[t & 1][g + 3][u]   = hB;
                } else {
                    s_h1[(t - 1) & 1][g][u]     = hA;
                    s_h1[(t - 1) & 1][g + 3][u] = hB;
                }
            }
        }
        __syncthreads();   // publish h; WAR-protect ex* and h buffers
    }

    // ---- final FC on h1(T-1), slot (T-1)&1 ----
    if (wid == 3 && lane < 60 && u == 0) {
        const int sl = (T_STEPS - 1) & 1;
        float oA = bfc[0], oB = bfc[0];
        #pragma unroll
        for (int j = 0; j < HS; ++j) {
            oA = fmaf(s_h1[sl][g][j],     wfc[j], oA);
            oB = fmaf(s_h1[sl][g + 3][j], wfc[j], oB);
        }
        out[bgA] = oA;
        if (okB) out[bgBr] = oB;
    }
}

extern "C" void kernel_launch(void* const* d_in, const int* in_sizes, int n_in,
                              void* d_out, int out_size, void* d_ws, size_t ws_size,
                              hipStream_t stream) {
    const float* x    = (const float*)d_in[0];
    const float* wih0 = (const float*)d_in[1];
    const float* whh0 = (const float*)d_in[2];
    const float* bih0 = (const float*)d_in[3];
    const float* bhh0 = (const float*)d_in[4];
    const float* wih1 = (const float*)d_in[5];
    const float* whh1 = (const float*)d_in[6];
    const float* bih1 = (const float*)d_in[7];
    const float* bhh1 = (const float*)d_in[8];
    const float* wfc  = (const float*)d_in[9];
    const float* bfc  = (const float*)d_in[10];
    float* out = (float*)d_out;

    dim3 grid(NBLK), block(256);
    hipLaunchKernelGGL(lstm2_fc_kernel, grid, block, 0, stream,
                       x, wih0, whh0, bih0, bhh0,
                       wih1, whh1, bih1, bhh1, wfc, bfc, out);
}